// Round 10
// baseline (217.140 us; speedup 1.0000x reference)
//
#include <hip/hip_runtime.h>
#include <hip/hip_bf16.h>

#define HDIM 256
#define HPDIM 128

typedef short bf8 __attribute__((ext_vector_type(8)));   // 8 bf16 in 4 VGPRs
typedef float f32x4 __attribute__((ext_vector_type(4)));

__device__ inline unsigned pkbf2(float a, float b) {
  float2 f; f.x = a; f.y = b;
  __hip_bfloat162 h = __float22bfloat162_rn(f);          // v_cvt_pk_bf16_f32 (RNE)
  unsigned u; __builtin_memcpy(&u, &h, 4); return u;
}
__device__ inline unsigned short bfbits(float v) {
  __hip_bfloat16 h = __float2bfloat16(v);
  unsigned short u; __builtin_memcpy(&u, &h, 2); return u;
}
__device__ inline uint4 pack8u(float4 a, float4 b) {
  uint4 r;
  r.x = pkbf2(a.x, a.y); r.y = pkbf2(a.z, a.w);
  r.z = pkbf2(b.x, b.y); r.w = pkbf2(b.z, b.w);
  return r;
}
__device__ inline float fast_tanh(float x) {
  float t = __expf(2.0f * x);
  return 1.0f - 2.0f * __builtin_amdgcn_rcpf(t + 1.0f);
}
// gather 8 consecutive fp32 weights -> bf16 MFMA fragment
__device__ inline bf8 wfrag(const float* __restrict__ s) {
  float4 a = *(const float4*)s, b = *(const float4*)(s + 4);
  uint4 u = pack8u(a, b);
  bf8 r; __builtin_memcpy(&r, &u, 16); return r;
}

typedef const __attribute__((address_space(1))) unsigned int* gas_ptr;
typedef __attribute__((address_space(3))) unsigned int* las_ptr;
__device__ inline void gld_lds16(const void* g, void* l) {
  __builtin_amdgcn_global_load_lds((gas_ptr)g, (las_ptr)l, 16, 0, 0);
}

// ---------------- Kernel 0: prep -----------------------------------------
// blocks 0..63 : front MLP (self-gathered weight fragments) -> x3f
// blocks 64..79: msg[b][h] -> msgTT[(h>>2)*4096 + b*4 + (h&3)]
__global__ __launch_bounds__(256) void k_prep(
    const float* __restrict__ h0, const float* __restrict__ htv,
    const float* __restrict__ cp,
    const float* __restrict__ w1, const float* __restrict__ w2,
    const float* __restrict__ w3, const float* __restrict__ msg,
    short* __restrict__ x3f, float* __restrict__ msgTT) {
  const int t = threadIdx.x;
  const int bx = blockIdx.x;

  if (bx >= 64) {                      // ---- msg transpose: 16 blocks
    const int b0 = (bx - 64) * 64;
    #pragma unroll
    for (int it = 0; it < 16; ++it) {
      int u = it * 256 + t;            // 4096 (g,b) float4 pairs
      int bl = u & 63, g = u >> 6;
      float4 v = *(const float4*)(msg + (size_t)(b0 + bl) * HDIM + g * 4);
      *(float4*)(msgTT + (size_t)g * 4096 + (b0 + bl) * 4) = v;   // coalesced write
    }
    return;
  }

  // ---- front MLP: 64 blocks x 16 b ----
  __shared__ char hbuf[8192];    // 16 x 256 bf16, swizzled 16B chunks
  __shared__ char xa[4096];      // 16 x 128 bf16, swizzled
  __shared__ char xb[4096];
  const int wave = t >> 6, lane = t & 63;
  const int r16 = lane & 15, quad = lane >> 4;
  const int b0 = bx * 16;
  const float cc = fminf(fmaxf(cp[0], 0.f), 1.f);

  // stage h = cc*h0+(1-cc)*ht (16x256)
  #pragma unroll
  for (int it = 0; it < 2; ++it) {
    int flat = it * 2048 + t * 8;
    int row = flat >> 8, col = flat & 255, kb = col >> 3;
    int gi = (b0 + row) * HDIM + col;
    float4 a = *(const float4*)(h0 + gi);
    float4 b = *(const float4*)(htv + gi);
    float4 va, vb;
    va.x = cc*a.x + (1.f-cc)*b.x; va.y = cc*a.y + (1.f-cc)*b.y;
    va.z = cc*a.z + (1.f-cc)*b.z; va.w = cc*a.w + (1.f-cc)*b.w;
    a = *(const float4*)(h0 + gi + 4); b = *(const float4*)(htv + gi + 4);
    vb.x = cc*a.x + (1.f-cc)*b.x; vb.y = cc*a.y + (1.f-cc)*b.y;
    vb.z = cc*a.z + (1.f-cc)*b.z; vb.w = cc*a.w + (1.f-cc)*b.w;
    *(uint4*)(hbuf + row*512 + ((kb ^ (row & 7)) << 4)) = pack8u(va, vb);
  }
  __syncthreads();

  // layer 1: [16 x 256] @ w1^T -> xa
  {
    f32x4 acc[2] = {};
    #pragma unroll
    for (int ks = 0; ks < 8; ++ks) {
      bf8 af = *(bf8*)(hbuf + r16*512 + (((ks*4 + quad) ^ (r16 & 7)) << 4));
      #pragma unroll
      for (int nt = 0; nt < 2; ++nt) {
        bf8 bw_ = wfrag(w1 + ((wave*2 + nt)*16 + r16) * 256 + ks*32 + quad*8);
        acc[nt] = __builtin_amdgcn_mfma_f32_16x16x32_bf16(af, bw_, acc[nt], 0, 0, 0);
      }
    }
    #pragma unroll
    for (int nt = 0; nt < 2; ++nt)
      #pragma unroll
      for (int i = 0; i < 4; ++i) {
        int row = quad*4 + i, col = wave*32 + nt*16 + r16;
        *(unsigned short*)(xa + row*256 + (((col >> 3) ^ (row & 7)) << 4) + ((col & 7) << 1))
            = bfbits(fast_tanh(acc[nt][i]));
      }
  }
  __syncthreads();
  // layer 2: xa @ w2^T -> xb
  {
    f32x4 acc[2] = {};
    #pragma unroll
    for (int ks = 0; ks < 4; ++ks) {
      bf8 af = *(bf8*)(xa + r16*256 + (((ks*4 + quad) ^ (r16 & 7)) << 4));
      #pragma unroll
      for (int nt = 0; nt < 2; ++nt) {
        bf8 bw_ = wfrag(w2 + ((wave*2 + nt)*16 + r16) * 128 + ks*32 + quad*8);
        acc[nt] = __builtin_amdgcn_mfma_f32_16x16x32_bf16(af, bw_, acc[nt], 0, 0, 0);
      }
    }
    #pragma unroll
    for (int nt = 0; nt < 2; ++nt)
      #pragma unroll
      for (int i = 0; i < 4; ++i) {
        int row = quad*4 + i, col = wave*32 + nt*16 + r16;
        *(unsigned short*)(xb + row*256 + (((col >> 3) ^ (row & 7)) << 4) + ((col & 7) << 1))
            = bfbits(fast_tanh(acc[nt][i]));
      }
  }
  __syncthreads();
  // layer 3: xb @ w3^T -> xa
  {
    f32x4 acc[2] = {};
    #pragma unroll
    for (int ks = 0; ks < 4; ++ks) {
      bf8 af = *(bf8*)(xb + r16*256 + (((ks*4 + quad) ^ (r16 & 7)) << 4));
      #pragma unroll
      for (int nt = 0; nt < 2; ++nt) {
        bf8 bw_ = wfrag(w3 + ((wave*2 + nt)*16 + r16) * 128 + ks*32 + quad*8);
        acc[nt] = __builtin_amdgcn_mfma_f32_16x16x32_bf16(af, bw_, acc[nt], 0, 0, 0);
      }
    }
    #pragma unroll
    for (int nt = 0; nt < 2; ++nt)
      #pragma unroll
      for (int i = 0; i < 4; ++i) {
        int row = quad*4 + i, col = wave*32 + nt*16 + r16;
        *(unsigned short*)(xa + row*256 + (((col >> 3) ^ (row & 7)) << 4) + ((col & 7) << 1))
            = bfbits(fast_tanh(acc[nt][i]));
      }
  }
  __syncthreads();
  // dump xa -> x3f in B-fragment order
  {
    int ks = t >> 6, l = t & 63, q2 = l >> 4, rr = l & 15;
    uint4 d = *(uint4*)(xa + rr*256 + (((ks*4 + q2) ^ (rr & 7)) << 4));
    *(uint4*)(x3f + (size_t)((bx*4 + ks)*64 + l)*8) = d;
  }
}

// ---------------- Kernel 1/2: fused hypernetwork GEMM --------------------
// PHASE 0: g1TT[k,b] = tanh( sum_h msgTT[h,b] * (fc4[kcol*256+h,:] . x3[b,:]) )
// PHASE 1: out[b,kcol] =     sum_k g1TT[k,b]  * (fc4[65536+kcol*256+k,:] . x3[b,:])
// Round-10 FIX: __launch_bounds__(1024, *1*). The second arg behaves with
// CUDA min-BLOCKS-per-CU semantics: (1024,4) => 64 waves/CU => 64-VGPR cap,
// which SPILLED the pinned xf[4][4] (64 VGPR) to scratch — rounds 4/8/9 all
// ran spilled (r9 counters: VGPR=64, WRITE 16->37 MB). (1024,1) => cap 256;
// LDS (98 KB) already limits to 1 block/CU, so occupancy is unchanged.
// Structure (merged DMA pipeline, r9) kept verbatim: chunk c DMA'd 2 rounds
// ahead via global_load_lds into fp32 ring, converted 1 round ahead into the
// swizzled bf16 slab, computed in round c; raw s_barrier + counted waits.
template<int PHASE>
__global__ __launch_bounds__(1024, 1) void k_hyper(
    const short* __restrict__ x3f, const float* __restrict__ wTT,
    const float* __restrict__ fc4, float* __restrict__ outp) {
  __shared__ char lds[65536 + 32768];      // bf16 slab (swizzled) + fp32 2-ring
  char* slab = lds;
  char* ring = lds + 65536;
  const int bxs = blockIdx.x;
  const int kcol = ((bxs & 7) << 5) | (bxs >> 3);   // bijective XCD grouping
  const int t = threadIdx.x, wave = t >> 6, lane = t & 63;
  const int r16 = lane & 15, quad = lane >> 4;
  const int bw = wave * 64;                // this wave's 64-b slice

  const float* src = fc4 + ((size_t)(PHASE ? 65536 : 0) + (size_t)kcol * 256) * HPDIM;

  // DMA chunk 0 first (start HBM early); 1 dwordx4/thread, linear dest
  gld_lds16(src + t * 4, ring + t * 16);

  // x3 B-fragments (16 x b128 per thread = 64 VGPRs), pinned live (no remat)
  bf8 xf[4][4];
  #pragma unroll
  for (int nt = 0; nt < 4; ++nt)
    #pragma unroll
    for (int ks = 0; ks < 4; ++ks)
      xf[nt][ks] = *(const bf8*)(x3f +
          (size_t)(((wave*4 + nt)*4 + ks)*64 + lane)*8);
  #pragma unroll
  for (int nt = 0; nt < 4; ++nt)
    #pragma unroll
    for (int ks = 0; ks < 4; ++ks)
      asm volatile("" : "+v"(xf[nt][ks]));

  // prologue: chunk 0 -> slab, DMA chunk 1
  asm volatile("s_waitcnt vmcnt(0) lgkmcnt(0)" ::: "memory");
  __builtin_amdgcn_sched_barrier(0);
  __builtin_amdgcn_s_barrier();            // chunk 0 fully in ring
  {
    f32x4 v = *(const f32x4*)(ring + t * 16);
    int row = t >> 5, kb = (t & 31) >> 1;
    uint2 o; o.x = pkbf2(v[0], v[1]); o.y = pkbf2(v[2], v[3]);
    *(uint2*)(slab + row * 256 + ((kb ^ (row & 7)) << 4) + (t & 1) * 8) = o;
  }
  gld_lds16(src + 4096 + t * 4, ring + 16384 + t * 16);   // chunk 1 in flight
  asm volatile("s_waitcnt lgkmcnt(0)" ::: "memory");
  __builtin_amdgcn_sched_barrier(0);
  __builtin_amdgcn_s_barrier();            // slab chunk 0 visible

  float gacc[4] = {0.f, 0.f, 0.f, 0.f};
  const float* wbase = wTT + (size_t)quad * 4096 + (bw + r16) * 4;

  #pragma unroll 1
  for (int c = 0; c < 8; ++c) {
    // ---- compute chunk c: h-groups 2c, 2c+1 ----
    #pragma unroll
    for (int hh = 0; hh < 2; ++hh) {
      const int hg = c * 2 + hh;
      float4 wv[4];
      #pragma unroll
      for (int nt = 0; nt < 4; ++nt)
        wv[nt] = *(const float4*)(wbase + (size_t)hg*16384 + nt*64);
      const int row = hg*16 + r16;
      bf8 af[4];
      #pragma unroll
      for (int ks = 0; ks < 4; ++ks)
        af[ks] = *(bf8*)(slab + row*256 + (((ks*4 + quad) ^ (row & 7)) << 4));
      #pragma unroll
      for (int nt = 0; nt < 4; ++nt) {
        f32x4 acc = {};
        #pragma unroll
        for (int ks = 0; ks < 4; ++ks)
          acc = __builtin_amdgcn_mfma_f32_16x16x32_bf16(af[ks], xf[nt][ks], acc, 0, 0, 0);
        gacc[nt] += acc[0]*wv[nt].x + acc[1]*wv[nt].y + acc[2]*wv[nt].z + acc[3]*wv[nt].w;
      }
    }
    // ---- pipeline maintenance ----
    if (c < 7) {
      // DMA(c+1) arrived (issued a full round ago; FIFO => compute's wv
      // waits already covered it). Explicit drain is ~free and safe.
      asm volatile("s_waitcnt vmcnt(0)" ::: "memory");
      __builtin_amdgcn_sched_barrier(0);
      if (c + 2 < 8)                       // issue AFTER the wait: stays in flight
        gld_lds16(src + (c + 2) * 4096 + t * 4, ring + ((c + 2) & 1) * 16384 + t * 16);
      __builtin_amdgcn_s_barrier();        // A: all waves done with chunk c reads
      {                                     // convert chunk c+1 (rows disjoint from c)
        f32x4 v = *(const f32x4*)(ring + ((c + 1) & 1) * 16384 + t * 16);
        int row = (c + 1) * 32 + (t >> 5), kb = (t & 31) >> 1;
        uint2 o; o.x = pkbf2(v[0], v[1]); o.y = pkbf2(v[2], v[3]);
        *(uint2*)(slab + row * 256 + ((kb ^ (row & 7)) << 4) + (t & 1) * 8) = o;
      }
      asm volatile("s_waitcnt lgkmcnt(0)" ::: "memory");
      __builtin_amdgcn_sched_barrier(0);
      __builtin_amdgcn_s_barrier();        // B: slab chunk c+1 visible
    }
  }

  #pragma unroll
  for (int nt = 0; nt < 4; ++nt) {
    float v = gacc[nt];
    v += __shfl_xor(v, 16);
    v += __shfl_xor(v, 32);
    if (quad == 0) {
      int b = bw + nt*16 + r16;
      if (PHASE == 0) outp[(size_t)(kcol >> 2)*4096 + b*4 + (kcol & 3)] = fast_tanh(v);
      else            outp[b*HDIM + kcol] = v;
    }
  }
}

extern "C" void kernel_launch(void* const* d_in, const int* in_sizes, int n_in,
                              void* d_out, int out_size, void* d_ws, size_t ws_size,
                              hipStream_t stream) {
  const float* h0  = (const float*)d_in[0];
  const float* htt = (const float*)d_in[1];
  const float* msg = (const float*)d_in[2];
  const float* c   = (const float*)d_in[3];
  const float* w1  = (const float*)d_in[4];
  const float* w2  = (const float*)d_in[5];
  const float* w3  = (const float*)d_in[6];
  const float* w4  = (const float*)d_in[7];
  float* out = (float*)d_out;

  short* x3f  = (short*)d_ws;                              // 256 KB
  float* g1TT = (float*)((char*)d_ws + 262144);            // 1 MB
  float* msgTT= (float*)((char*)d_ws + 262144 + 1048576);  // 1 MB

  k_prep<<<dim3(80), dim3(256), 0, stream>>>(h0, htt, c, w1, w2, w3, msg,
                                             x3f, msgTT);
  k_hyper<0><<<dim3(256), dim3(1024), 0, stream>>>(x3f, msgTT, w4, g1TT);
  k_hyper<1><<<dim3(256), dim3(1024), 0, stream>>>(x3f, g1TT, w4, out);
}

// Round 11
// 159.377 us; speedup vs baseline: 1.3624x; 1.3624x over previous
//
#include <hip/hip_runtime.h>
#include <hip/hip_bf16.h>

#define HDIM 256
#define HPDIM 128

typedef short bf8 __attribute__((ext_vector_type(8)));   // 8 bf16 in 4 VGPRs
typedef float f32x4 __attribute__((ext_vector_type(4)));

__device__ inline unsigned pkbf2(float a, float b) {
  float2 f; f.x = a; f.y = b;
  __hip_bfloat162 h = __float22bfloat162_rn(f);          // v_cvt_pk_bf16_f32 (RNE)
  unsigned u; __builtin_memcpy(&u, &h, 4); return u;
}
__device__ inline unsigned short bfbits(float v) {
  __hip_bfloat16 h = __float2bfloat16(v);
  unsigned short u; __builtin_memcpy(&u, &h, 2); return u;
}
__device__ inline uint4 pack8u(float4 a, float4 b) {
  uint4 r;
  r.x = pkbf2(a.x, a.y); r.y = pkbf2(a.z, a.w);
  r.z = pkbf2(b.x, b.y); r.w = pkbf2(b.z, b.w);
  return r;
}
__device__ inline float fast_tanh(float x) {
  float t = __expf(2.0f * x);
  return 1.0f - 2.0f * __builtin_amdgcn_rcpf(t + 1.0f);
}
// gather 8 consecutive fp32 weights -> bf16 MFMA fragment
__device__ inline bf8 wfrag(const float* __restrict__ s) {
  float4 a = *(const float4*)s, b = *(const float4*)(s + 4);
  uint4 u = pack8u(a, b);
  bf8 r; __builtin_memcpy(&r, &u, 16); return r;
}

typedef const __attribute__((address_space(1))) unsigned int* gas_ptr;
typedef __attribute__((address_space(3))) unsigned int* las_ptr;
__device__ inline void gld_lds16(const void* g, void* l) {
  __builtin_amdgcn_global_load_lds((gas_ptr)g, (las_ptr)l, 16, 0, 0);
}

// ---------------- Kernel 0: prep -----------------------------------------
// blocks 0..63 : front MLP (self-gathered weight fragments) -> x3f
// blocks 64..79: msg[b][h] -> msgTT[(h>>2)*4096 + b*4 + (h&3)]
__global__ __launch_bounds__(256) void k_prep(
    const float* __restrict__ h0, const float* __restrict__ htv,
    const float* __restrict__ cp,
    const float* __restrict__ w1, const float* __restrict__ w2,
    const float* __restrict__ w3, const float* __restrict__ msg,
    short* __restrict__ x3f, float* __restrict__ msgTT) {
  const int t = threadIdx.x;
  const int bx = blockIdx.x;

  if (bx >= 64) {                      // ---- msg transpose: 16 blocks
    const int b0 = (bx - 64) * 64;
    #pragma unroll
    for (int it = 0; it < 16; ++it) {
      int u = it * 256 + t;            // 4096 (g,b) float4 pairs
      int bl = u & 63, g = u >> 6;
      float4 v = *(const float4*)(msg + (size_t)(b0 + bl) * HDIM + g * 4);
      *(float4*)(msgTT + (size_t)g * 4096 + (b0 + bl) * 4) = v;   // coalesced write
    }
    return;
  }

  // ---- front MLP: 64 blocks x 16 b ----
  __shared__ char hbuf[8192];    // 16 x 256 bf16, swizzled 16B chunks
  __shared__ char xa[4096];      // 16 x 128 bf16, swizzled
  __shared__ char xb[4096];
  const int wave = t >> 6, lane = t & 63;
  const int r16 = lane & 15, quad = lane >> 4;
  const int b0 = bx * 16;
  const float cc = fminf(fmaxf(cp[0], 0.f), 1.f);

  // stage h = cc*h0+(1-cc)*ht (16x256)
  #pragma unroll
  for (int it = 0; it < 2; ++it) {
    int flat = it * 2048 + t * 8;
    int row = flat >> 8, col = flat & 255, kb = col >> 3;
    int gi = (b0 + row) * HDIM + col;
    float4 a = *(const float4*)(h0 + gi);
    float4 b = *(const float4*)(htv + gi);
    float4 va, vb;
    va.x = cc*a.x + (1.f-cc)*b.x; va.y = cc*a.y + (1.f-cc)*b.y;
    va.z = cc*a.z + (1.f-cc)*b.z; va.w = cc*a.w + (1.f-cc)*b.w;
    a = *(const float4*)(h0 + gi + 4); b = *(const float4*)(htv + gi + 4);
    vb.x = cc*a.x + (1.f-cc)*b.x; vb.y = cc*a.y + (1.f-cc)*b.y;
    vb.z = cc*a.z + (1.f-cc)*b.z; vb.w = cc*a.w + (1.f-cc)*b.w;
    *(uint4*)(hbuf + row*512 + ((kb ^ (row & 7)) << 4)) = pack8u(va, vb);
  }
  __syncthreads();

  // layer 1: [16 x 256] @ w1^T -> xa
  {
    f32x4 acc[2] = {};
    #pragma unroll
    for (int ks = 0; ks < 8; ++ks) {
      bf8 af = *(bf8*)(hbuf + r16*512 + (((ks*4 + quad) ^ (r16 & 7)) << 4));
      #pragma unroll
      for (int nt = 0; nt < 2; ++nt) {
        bf8 bw_ = wfrag(w1 + ((wave*2 + nt)*16 + r16) * 256 + ks*32 + quad*8);
        acc[nt] = __builtin_amdgcn_mfma_f32_16x16x32_bf16(af, bw_, acc[nt], 0, 0, 0);
      }
    }
    #pragma unroll
    for (int nt = 0; nt < 2; ++nt)
      #pragma unroll
      for (int i = 0; i < 4; ++i) {
        int row = quad*4 + i, col = wave*32 + nt*16 + r16;
        *(unsigned short*)(xa + row*256 + (((col >> 3) ^ (row & 7)) << 4) + ((col & 7) << 1))
            = bfbits(fast_tanh(acc[nt][i]));
      }
  }
  __syncthreads();
  // layer 2: xa @ w2^T -> xb
  {
    f32x4 acc[2] = {};
    #pragma unroll
    for (int ks = 0; ks < 4; ++ks) {
      bf8 af = *(bf8*)(xa + r16*256 + (((ks*4 + quad) ^ (r16 & 7)) << 4));
      #pragma unroll
      for (int nt = 0; nt < 2; ++nt) {
        bf8 bw_ = wfrag(w2 + ((wave*2 + nt)*16 + r16) * 128 + ks*32 + quad*8);
        acc[nt] = __builtin_amdgcn_mfma_f32_16x16x32_bf16(af, bw_, acc[nt], 0, 0, 0);
      }
    }
    #pragma unroll
    for (int nt = 0; nt < 2; ++nt)
      #pragma unroll
      for (int i = 0; i < 4; ++i) {
        int row = quad*4 + i, col = wave*32 + nt*16 + r16;
        *(unsigned short*)(xb + row*256 + (((col >> 3) ^ (row & 7)) << 4) + ((col & 7) << 1))
            = bfbits(fast_tanh(acc[nt][i]));
      }
  }
  __syncthreads();
  // layer 3: xb @ w3^T -> xa
  {
    f32x4 acc[2] = {};
    #pragma unroll
    for (int ks = 0; ks < 4; ++ks) {
      bf8 af = *(bf8*)(xb + r16*256 + (((ks*4 + quad) ^ (r16 & 7)) << 4));
      #pragma unroll
      for (int nt = 0; nt < 2; ++nt) {
        bf8 bw_ = wfrag(w3 + ((wave*2 + nt)*16 + r16) * 128 + ks*32 + quad*8);
        acc[nt] = __builtin_amdgcn_mfma_f32_16x16x32_bf16(af, bw_, acc[nt], 0, 0, 0);
      }
    }
    #pragma unroll
    for (int nt = 0; nt < 2; ++nt)
      #pragma unroll
      for (int i = 0; i < 4; ++i) {
        int row = quad*4 + i, col = wave*32 + nt*16 + r16;
        *(unsigned short*)(xa + row*256 + (((col >> 3) ^ (row & 7)) << 4) + ((col & 7) << 1))
            = bfbits(fast_tanh(acc[nt][i]));
      }
  }
  __syncthreads();
  // dump xa -> x3f in B-fragment order
  {
    int ks = t >> 6, l = t & 63, q2 = l >> 4, rr = l & 15;
    uint4 d = *(uint4*)(xa + rr*256 + (((ks*4 + q2) ^ (rr & 7)) << 4));
    *(uint4*)(x3f + (size_t)((bx*4 + ks)*64 + l)*8) = d;
  }
}

// ---------------- Kernel 1/2: fused hypernetwork GEMM --------------------
// PHASE 0: g1TT[k,b] = tanh( sum_h msgTT[h,b] * (fc4[kcol*256+h,:] . x3[b,:]) )
// PHASE 1: out[b,kcol] =     sum_k g1TT[k,b]  * (fc4[65536+kcol*256+k,:] . x3[b,:])
// Round-11: 512-THREAD blocks. Empirical allocator rule on this toolchain
// (6 data points): 1024-thr kernels get 64 VGPRs (xf spills -> 37 MB scratch
// writes, the real cause of the 31-61 us plateau); 512-thr kernels get 128.
// Footprint ~115 fits 128 -> first spill-free run. Block = 1 kcol x 512 b
// (8 waves x 64 b). Grid 512: h = bxs>>8, so a kcol's two b-half blocks are
// 256 apart -> same XCD (256%8==0), co-resident (80 KB LDS -> 2 blocks/CU)
// -> twin slab DMA dedups in L2, HBM fetch stays ~1x. 16-round pipeline:
// chunk c (16 rows = 1 h-group, 8 KB) DMA'd 2 ahead, converted 1 ahead,
// computed in round c; ONE barrier/round (slab rows disjoint; ring reads
// are own-wave). 2 blocks/CU TLP covers pipeline bubbles.
template<int PHASE>
__global__ __launch_bounds__(512, 2) void k_hyper(
    const short* __restrict__ x3f, const float* __restrict__ wTT,
    const float* __restrict__ fc4, float* __restrict__ outp) {
  __shared__ char lds[65536 + 16384];      // bf16 slab (swizzled) + fp32 2-ring
  char* slab = lds;
  char* ring = lds + 65536;
  const int bxs = blockIdx.x;
  const int h = bxs >> 8;                  // b-half (twin blocks 256 apart)
  const int p = bxs & 255;
  const int kcol = ((p & 7) << 5) | (p >> 3);   // bijective XCD grouping
  const int t = threadIdx.x, wave = t >> 6, lane = t & 63;
  const int r16 = lane & 15, quad = lane >> 4;
  const int bw = h * 512 + wave * 64;      // this wave's 64-b slice

  const float* src = fc4 + ((size_t)(PHASE ? 65536 : 0) + (size_t)kcol * 256) * HPDIM;

  // DMA chunk 0 (16 rows, 8 KB; 1 dwordx4/thread, linear dest)
  gld_lds16(src + t * 4, ring + t * 16);

  // x3 B-fragments (16 x b128 per thread = 64 VGPRs), pinned live (no remat)
  bf8 xf[4][4];
  #pragma unroll
  for (int nt = 0; nt < 4; ++nt)
    #pragma unroll
    for (int ks = 0; ks < 4; ++ks)
      xf[nt][ks] = *(const bf8*)(x3f +
          (size_t)(((h*32 + wave*4 + nt)*4 + ks)*64 + lane)*8);
  #pragma unroll
  for (int nt = 0; nt < 4; ++nt)
    #pragma unroll
    for (int ks = 0; ks < 4; ++ks)
      asm volatile("" : "+v"(xf[nt][ks]));

  // prologue: chunk 0 -> slab, DMA chunk 1, barrier
  asm volatile("s_waitcnt vmcnt(0) lgkmcnt(0)" ::: "memory");
  __builtin_amdgcn_sched_barrier(0);
  {
    f32x4 v = *(const f32x4*)(ring + t * 16);
    int row = t >> 5, kb = (t & 31) >> 1;
    uint2 o; o.x = pkbf2(v[0], v[1]); o.y = pkbf2(v[2], v[3]);
    *(uint2*)(slab + row * 256 + ((kb ^ (row & 7)) << 4) + (t & 1) * 8) = o;
  }
  gld_lds16(src + 2048 + t * 4, ring + 8192 + t * 16);   // chunk 1 in flight
  asm volatile("s_waitcnt lgkmcnt(0)" ::: "memory");
  __builtin_amdgcn_sched_barrier(0);
  __builtin_amdgcn_s_barrier();            // slab rows 0..15 visible

  float gacc[4] = {0.f, 0.f, 0.f, 0.f};
  const float* wbase = wTT + (size_t)quad * 4096 + (bw + r16) * 4;

  #pragma unroll 1
  for (int c = 0; c < 16; ++c) {
    // ---- compute h-group c (rows 16c..16c+15) ----
    {
      float4 wv[4];
      #pragma unroll
      for (int nt = 0; nt < 4; ++nt)
        wv[nt] = *(const float4*)(wbase + (size_t)c*16384 + nt*64);
      const int row = c*16 + r16;
      bf8 af[4];
      #pragma unroll
      for (int ks = 0; ks < 4; ++ks)
        af[ks] = *(bf8*)(slab + row*256 + (((ks*4 + quad) ^ (r16 & 7)) << 4));
      #pragma unroll
      for (int nt = 0; nt < 4; ++nt) {
        f32x4 acc = {};
        #pragma unroll
        for (int ks = 0; ks < 4; ++ks)
          acc = __builtin_amdgcn_mfma_f32_16x16x32_bf16(af[ks], xf[nt][ks], acc, 0, 0, 0);
        gacc[nt] += acc[0]*wv[nt].x + acc[1]*wv[nt].y + acc[2]*wv[nt].z + acc[3]*wv[nt].w;
      }
    }
    // ---- pipeline maintenance (no slab/ring hazard needs a 2nd barrier:
    //      convert(c+1) writes rows disjoint from compute(c); ring slot of
    //      DMA(c+2) was last read by own-wave convert(c) a full round ago) ----
    if (c < 15) {
      asm volatile("s_waitcnt vmcnt(0)" ::: "memory");   // DMA(c+1) arrived
      __builtin_amdgcn_sched_barrier(0);
      if (c + 2 < 16)                      // issue AFTER wait: stays in flight
        gld_lds16(src + (c + 2) * 2048 + t * 4, ring + ((c + 2) & 1) * 8192 + t * 16);
      {                                     // convert chunk c+1
        f32x4 v = *(const f32x4*)(ring + ((c + 1) & 1) * 8192 + t * 16);
        int row = (c + 1) * 16 + (t >> 5), kb = (t & 31) >> 1;
        uint2 o; o.x = pkbf2(v[0], v[1]); o.y = pkbf2(v[2], v[3]);
        *(uint2*)(slab + row * 256 + ((kb ^ ((t >> 5) & 7)) << 4) + (t & 1) * 8) = o;
      }
      asm volatile("s_waitcnt lgkmcnt(0)" ::: "memory");
      __builtin_amdgcn_sched_barrier(0);
      __builtin_amdgcn_s_barrier();        // slab chunk c+1 visible to all waves
    }
  }

  #pragma unroll
  for (int nt = 0; nt < 4; ++nt) {
    float v = gacc[nt];
    v += __shfl_xor(v, 16);
    v += __shfl_xor(v, 32);
    if (quad == 0) {
      int b = bw + nt*16 + r16;
      if (PHASE == 0) outp[(size_t)(kcol >> 2)*4096 + b*4 + (kcol & 3)] = fast_tanh(v);
      else            outp[b*HDIM + kcol] = v;
    }
  }
}

extern "C" void kernel_launch(void* const* d_in, const int* in_sizes, int n_in,
                              void* d_out, int out_size, void* d_ws, size_t ws_size,
                              hipStream_t stream) {
  const float* h0  = (const float*)d_in[0];
  const float* htt = (const float*)d_in[1];
  const float* msg = (const float*)d_in[2];
  const float* c   = (const float*)d_in[3];
  const float* w1  = (const float*)d_in[4];
  const float* w2  = (const float*)d_in[5];
  const float* w3  = (const float*)d_in[6];
  const float* w4  = (const float*)d_in[7];
  float* out = (float*)d_out;

  short* x3f  = (short*)d_ws;                              // 256 KB
  float* g1TT = (float*)((char*)d_ws + 262144);            // 1 MB
  float* msgTT= (float*)((char*)d_ws + 262144 + 1048576);  // 1 MB

  k_prep<<<dim3(80), dim3(256), 0, stream>>>(h0, htt, c, w1, w2, w3, msg,
                                             x3f, msgTT);
  k_hyper<0><<<dim3(512), dim3(512), 0, stream>>>(x3f, msgTT, w4, g1TT);
  k_hyper<1><<<dim3(512), dim3(512), 0, stream>>>(x3f, g1TT, w4, out);
}